// Round 2
// baseline (2488.775 us; speedup 1.0000x reference)
//
#include <hip/hip_runtime.h>

typedef unsigned short u16;
typedef short v8s __attribute__((ext_vector_type(8)));
typedef u16 v8u __attribute__((ext_vector_type(8)));
typedef float v4f __attribute__((ext_vector_type(4)));
typedef __bf16 v8bf __attribute__((ext_vector_type(8)));

__device__ __forceinline__ float bf2f(u16 u) {
    unsigned x = ((unsigned)u) << 16; float f; __builtin_memcpy(&f, &x, 4); return f;
}
__device__ __forceinline__ u16 f2bf(float f) {
    unsigned x; __builtin_memcpy(&x, &f, 4);
    x = x + 0x7FFFu + ((x >> 16) & 1u);
    return (u16)(x >> 16);
}
__device__ __forceinline__ float silu(float v) { return v / (1.f + __expf(-v)); }

// ---------------------------------------------------------------------------
// Weight conversion / reshuffle kernels (fp32 in -> bf16 out)
// ---------------------------------------------------------------------------
__global__ void cvtw(const float* __restrict__ in, u16* __restrict__ out, int n) {
    int i = blockIdx.x * 256 + threadIdx.x;
    if (i < n) out[i] = f2bf(in[i]);
}
// 3x3: in[co][ci][tap(9)] -> out[tap][co][ci]   (128x128x9)
__global__ void wtrans3(const float* __restrict__ in, u16* __restrict__ out) {
    int i = blockIdx.x * 256 + threadIdx.x;
    if (i >= 147456) return;
    int tap = i % 9; int rem = i / 9; int ci = rem & 127; int co = rem >> 7;
    out[((tap * 128 + co) << 7) + ci] = f2bf(in[i]);
}
// pixel-unshuffle 1x1: in[co][c*R2+tap] -> out[tap][co][c]  (co=128, c=128)
__global__ void wtrans_ps(const float* __restrict__ in, u16* __restrict__ out, int R2) {
    int i = blockIdx.x * 256 + threadIdx.x;
    int tap = i % R2; int rem = i / R2; int c = rem & 127; int co = rem >> 7;
    out[((tap * 128 + co) << 7) + c] = f2bf(in[i]);
}

// ---------------------------------------------------------------------------
// NCHW fp32 -> NHWC bf16 transpose for x (C=256, HW=16384)
// ---------------------------------------------------------------------------
__global__ __launch_bounds__(256) void nchw2nhwc(const float* __restrict__ in, u16* __restrict__ out) {
    __shared__ u16 tile[64][72];
    const int n = blockIdx.z, c0 = blockIdx.y * 64, p0 = blockIdx.x * 64;
#pragma unroll
    for (int rep = 0; rep < 16; ++rep) {
        int idx = rep * 256 + threadIdx.x;
        int c = idx >> 6, p = idx & 63;
        tile[c][p] = f2bf(in[((size_t)(n * 256 + c0 + c)) * 16384 + p0 + p]);
    }
    __syncthreads();
#pragma unroll
    for (int rep = 0; rep < 16; ++rep) {
        int idx = rep * 256 + threadIdx.x;
        int p = idx >> 6, c = idx & 63;
        out[((size_t)n * 16384 + p0 + p) * 256 + c0 + c] = tile[c][p];
    }
}

// ---------------------------------------------------------------------------
// Generic MFMA conv (NHWC bf16), taps KHxKW, stride S, pad PAD, Cin=CIN/tap.
// Tile: 64 hw (M) x 64 co (N) per block of 4 waves (each wave 32x32).
// Fused: scale, bias, SiLU (fp32). Output NHWC bf16.
// ---------------------------------------------------------------------------
template <int KH, int KW, int S, int PAD, int CIN>
__global__ __launch_bounds__(256) void conv_mfma(
    const u16* __restrict__ src, int c0, int srcC,
    const u16* __restrict__ wt,
    const float* __restrict__ scale, const float* __restrict__ bias,
    u16* __restrict__ out, int Hin, int Win, int Wout, int Cout) {
    const int n = blockIdx.z;
    const int co0 = blockIdx.y * 64;
    const int hw0 = blockIdx.x * 64;
    const int tid = threadIdx.x;
    const int lane = tid & 63, wv = tid >> 6;
    const int r = lane & 15, q = lane >> 4;
    const int wr = wv >> 1, wc = wv & 1;

    const int m0 = hw0 + wr * 32 + r;
    const int m1 = m0 + 16;
    const int h0 = m0 / Wout, w0 = m0 - h0 * Wout;
    const int h1 = m1 / Wout, w1 = m1 - h1 * Wout;

    v4f acc00 = {0.f, 0.f, 0.f, 0.f}, acc01 = {0.f, 0.f, 0.f, 0.f};
    v4f acc10 = {0.f, 0.f, 0.f, 0.f}, acc11 = {0.f, 0.f, 0.f, 0.f};

    const u16* b0base = wt + (size_t)(co0 + wc * 32 + r) * CIN + q * 8;
    const size_t wtap = (size_t)Cout * CIN;

    int tap = 0;
#pragma unroll
    for (int kh = 0; kh < KH; ++kh)
#pragma unroll
        for (int kw = 0; kw < KW; ++kw, ++tap) {
            int ih0 = h0 * S + kh - PAD, iw0 = w0 * S + kw - PAD;
            int ih1 = h1 * S + kh - PAD, iw1 = w1 * S + kw - PAD;
            bool v0 = ((unsigned)ih0 < (unsigned)Hin) & ((unsigned)iw0 < (unsigned)Win);
            bool v1 = ((unsigned)ih1 < (unsigned)Hin) & ((unsigned)iw1 < (unsigned)Win);
            int p0i = v0 ? (n * Hin + ih0) * Win + iw0 : 0;
            int p1i = v1 ? (n * Hin + ih1) * Win + iw1 : 0;
            const u16* a0 = src + (size_t)p0i * srcC + c0 + q * 8;
            const u16* a1 = src + (size_t)p1i * srcC + c0 + q * 8;
            const u16* b0 = b0base + (size_t)tap * wtap;
            const u16* b1 = b0 + (size_t)16 * CIN;
#pragma unroll
            for (int k = 0; k < CIN; k += 32) {
                v8s za = {0, 0, 0, 0, 0, 0, 0, 0};
                v8s a0s = za, a1s = za;
                if (v0) a0s = *(const v8s*)(a0 + k);
                if (v1) a1s = *(const v8s*)(a1 + k);
                v8s b0s = *(const v8s*)(b0 + k);
                v8s b1s = *(const v8s*)(b1 + k);
                v8bf af0 = __builtin_bit_cast(v8bf, a0s);
                v8bf af1 = __builtin_bit_cast(v8bf, a1s);
                v8bf bw0 = __builtin_bit_cast(v8bf, b0s);
                v8bf bw1 = __builtin_bit_cast(v8bf, b1s);
                acc00 = __builtin_amdgcn_mfma_f32_16x16x32_bf16(af0, bw0, acc00, 0, 0, 0);
                acc01 = __builtin_amdgcn_mfma_f32_16x16x32_bf16(af0, bw1, acc01, 0, 0, 0);
                acc10 = __builtin_amdgcn_mfma_f32_16x16x32_bf16(af1, bw0, acc10, 0, 0, 0);
                acc11 = __builtin_amdgcn_mfma_f32_16x16x32_bf16(af1, bw1, acc11, 0, 0, 0);
            }
        }

    const int HWo = gridDim.x * 64;
#pragma unroll
    for (int ct = 0; ct < 2; ++ct) {
        v4f av0 = ct ? acc01 : acc00;
        v4f av1 = ct ? acc11 : acc10;
        int co = co0 + wc * 32 + ct * 16 + r;
        float s = scale[co], bb = bias[co];
        int mb = hw0 + wr * 32 + q * 4;
#pragma unroll
        for (int i = 0; i < 4; ++i) {
            float x0 = av0[i] * s + bb;
            float x1 = av1[i] * s + bb;
            out[((size_t)n * HWo + mb + i) * Cout + co] = f2bf(silu(x0));
            out[((size_t)n * HWo + mb + 16 + i) * Cout + co] = f2bf(silu(x1));
        }
    }
}

// ---------------------------------------------------------------------------
// cv2: 1x1 conv over implicit concat [t(256ch), y1, y2, y3] -> 256 ch,
// writes d_out directly in NCHW fp32 (float4 16B stores).
// ---------------------------------------------------------------------------
__global__ __launch_bounds__(256) void conv_cat_mfma(
    const u16* __restrict__ s0, const u16* __restrict__ s1,
    const u16* __restrict__ s2, const u16* __restrict__ s3,
    const u16* __restrict__ wt,  // [256][640] bf16
    const float* __restrict__ scale, const float* __restrict__ bias,
    float* __restrict__ out) {
    const int n = blockIdx.z, co0 = blockIdx.y * 64, hw0 = blockIdx.x * 64;
    const int tid = threadIdx.x, lane = tid & 63, wv = tid >> 6;
    const int r = lane & 15, q = lane >> 4, wr = wv >> 1, wc = wv & 1;
    const int m0 = hw0 + wr * 32 + r, m1 = m0 + 16;

    v4f acc00 = {0.f, 0.f, 0.f, 0.f}, acc01 = {0.f, 0.f, 0.f, 0.f};
    v4f acc10 = {0.f, 0.f, 0.f, 0.f}, acc11 = {0.f, 0.f, 0.f, 0.f};

    const u16* srcs[4] = {s0, s1, s2, s3};
    const int sC[4] = {256, 128, 128, 128};
    const int kb[4] = {0, 256, 384, 512};
    const u16* brow = wt + (size_t)(co0 + wc * 32 + r) * 640 + q * 8;

#pragma unroll
    for (int si = 0; si < 4; ++si) {
        const u16* a0 = srcs[si] + ((size_t)n * 16384 + m0) * sC[si] + q * 8;
        const u16* a1 = srcs[si] + ((size_t)n * 16384 + m1) * sC[si] + q * 8;
        const u16* b0 = brow + kb[si];
        const u16* b1 = b0 + 16 * 640;
#pragma unroll
        for (int k = 0; k < 256; k += 32) {
            if (si > 0 && k >= 128) break;
            v8s a0s = *(const v8s*)(a0 + k);
            v8s a1s = *(const v8s*)(a1 + k);
            v8s b0s = *(const v8s*)(b0 + k);
            v8s b1s = *(const v8s*)(b1 + k);
            v8bf af0 = __builtin_bit_cast(v8bf, a0s);
            v8bf af1 = __builtin_bit_cast(v8bf, a1s);
            v8bf bw0 = __builtin_bit_cast(v8bf, b0s);
            v8bf bw1 = __builtin_bit_cast(v8bf, b1s);
            acc00 = __builtin_amdgcn_mfma_f32_16x16x32_bf16(af0, bw0, acc00, 0, 0, 0);
            acc01 = __builtin_amdgcn_mfma_f32_16x16x32_bf16(af0, bw1, acc01, 0, 0, 0);
            acc10 = __builtin_amdgcn_mfma_f32_16x16x32_bf16(af1, bw0, acc10, 0, 0, 0);
            acc11 = __builtin_amdgcn_mfma_f32_16x16x32_bf16(af1, bw1, acc11, 0, 0, 0);
        }
    }

#pragma unroll
    for (int ct = 0; ct < 2; ++ct) {
        v4f av0 = ct ? acc01 : acc00;
        v4f av1 = ct ? acc11 : acc10;
        int co = co0 + wc * 32 + ct * 16 + r;
        float s = scale[co], bb = bias[co];
        int mb = hw0 + wr * 32 + q * 4;
        v4f o0, o1;
#pragma unroll
        for (int i = 0; i < 4; ++i) {
            o0[i] = silu(av0[i] * s + bb);
            o1[i] = silu(av1[i] * s + bb);
        }
        size_t base = (size_t)(n * 256 + co) * 16384;
        *(v4f*)(out + base + mb) = o0;
        *(v4f*)(out + base + mb + 16) = o1;
    }
}

// ---------------------------------------------------------------------------
// u2 carafe == nearest 2x upsample (+ residual y1). NHWC bf16, C=128.
// ---------------------------------------------------------------------------
__global__ __launch_bounds__(256) void k_upadd(const u16* __restrict__ y2a,
                                               const u16* __restrict__ y1,
                                               u16* __restrict__ out) {
    int t = blockIdx.x * 256 + threadIdx.x;  // 2,097,152
    int cg = t & 15; int pix = t >> 4;
    int n = pix >> 14; int p = pix & 16383; int ho = p >> 7; int wo = p & 127;
    const u16* a = y2a + ((size_t)((n * 64 + (ho >> 1)) * 64 + (wo >> 1))) * 128 + cg * 8;
    const u16* b = y1 + (size_t)pix * 128 + cg * 8;
    v8s av = *(const v8s*)a;
    v8s bv = *(const v8s*)b;
    v8u o;
#pragma unroll
    for (int e = 0; e < 8; ++e) o[e] = f2bf(bf2f((u16)av[e]) + bf2f((u16)bv[e]));
    *(v8u*)(out + (size_t)pix * 128 + cg * 8) = o;
}

// ---------------------------------------------------------------------------
// u3 carafe pieces (small spatial, scalar fp32 math)
// ---------------------------------------------------------------------------
// 1x1 conv 128->32 on y3a (NHWC bf16 8x32x32x128) -> ktA fp32 [pix][32]
__global__ __launch_bounds__(256) void k_u3down(const u16* __restrict__ y3a,
                                                const float* __restrict__ w,
                                                const float* __restrict__ b,
                                                float* __restrict__ ktA) {
    int t = blockIdx.x * 256 + threadIdx.x;  // 262,144
    int co = t & 31; int pix = t >> 5;
    const u16* xr = y3a + (size_t)pix * 128;
    const float* wr = w + (size_t)co * 128;
    float acc = b[co];
#pragma unroll 16
    for (int k = 0; k < 128; ++k) acc += bf2f(xr[k]) * wr[k];
    ktA[t] = acc;
}

// 2x2 conv (top-left pad 1) 32->64 + softmax over kk at co = kk*16 + r
// -> wtsm [pix][r][kk] fp32
__global__ __launch_bounds__(256) void k_u3enc(const float* __restrict__ ktA,
                                               const float* __restrict__ ew,
                                               const float* __restrict__ eb,
                                               float* __restrict__ wtsm) {
    int t = blockIdx.x * 256 + threadIdx.x;  // 131,072
    int r = t & 15; int pix = t >> 4;
    int n = pix >> 10; int hw = pix & 1023; int h = hw >> 5; int w = hw & 31;
    float v[4];
#pragma unroll
    for (int kk = 0; kk < 4; ++kk) {
        int co = kk * 16 + r;
        float acc = eb[co];
#pragma unroll
        for (int dh = 0; dh < 2; ++dh)
#pragma unroll
            for (int dw = 0; dw < 2; ++dw) {
                int hh = h - 1 + dh, ww = w - 1 + dw;
                if (hh < 0 || ww < 0) continue;
                const float* kp = ktA + ((size_t)((n * 32 + hh) * 32 + ww)) * 32;
                const float* wp = ew + (size_t)co * 128 + dh * 2 + dw;  // ew[co][ci][dh][dw]
                for (int ci = 0; ci < 32; ++ci) acc += kp[ci] * wp[ci * 4];
            }
        v[kk] = acc;
    }
    float mx = fmaxf(fmaxf(v[0], v[1]), fmaxf(v[2], v[3]));
    float e0 = __expf(v[0] - mx), e1 = __expf(v[1] - mx), e2 = __expf(v[2] - mx), e3 = __expf(v[3] - mx);
    float inv = 1.f / (e0 + e1 + e2 + e3);
    float* o = wtsm + (size_t)t * 4;
    o[0] = e0 * inv; o[1] = e1 * inv; o[2] = e2 * inv; o[3] = e3 * inv;
}

// combine: out[n,4h+i,4w+j,c] = sum_kk wtsm[..] * y3a[n,h+ki-1,w+kj-1,c] + y2[..]
__global__ __launch_bounds__(256) void k_carafe(const u16* __restrict__ y3a,
                                                const float* __restrict__ wtsm,
                                                const u16* __restrict__ y2,
                                                u16* __restrict__ out) {
    int t = blockIdx.x * 256 + threadIdx.x;  // 2,097,152
    int cg = t & 15; int pix = t >> 4;
    int n = pix >> 14; int p = pix & 16383; int ho = p >> 7; int wo = p & 127;
    int h = ho >> 2, i = ho & 3, w = wo >> 2, j = wo & 3, r = i * 4 + j;
    const float* wv = wtsm + ((size_t)((n * 1024 + h * 32 + w) * 16 + r)) * 4;
    v8s yv = *(const v8s*)(y2 + (size_t)pix * 128 + cg * 8);
    float acc[8];
#pragma unroll
    for (int e = 0; e < 8; ++e) acc[e] = bf2f((u16)yv[e]);
#pragma unroll
    for (int kk = 0; kk < 4; ++kk) {
        int ki = kk >> 1, kj = kk & 1;
        int hh = h + ki - 1, ww = w + kj - 1;
        if (hh < 0 || ww < 0) continue;
        float wk = wv[kk];
        v8s sv = *(const v8s*)(y3a + ((size_t)((n * 32 + hh) * 32 + ww)) * 128 + cg * 8);
#pragma unroll
        for (int e = 0; e < 8; ++e) acc[e] += wk * bf2f((u16)sv[e]);
    }
    v8u o;
#pragma unroll
    for (int e = 0; e < 8; ++e) o[e] = f2bf(acc[e]);
    *(v8u*)(out + (size_t)pix * 128 + cg * 8) = o;
}

// ---------------------------------------------------------------------------
extern "C" void kernel_launch(void* const* d_in, const int* in_sizes, int n_in,
                              void* d_out, int out_size, void* d_ws, size_t ws_size,
                              hipStream_t stream) {
    const float* x     = (const float*)d_in[0];
    const float* cv1_w = (const float*)d_in[1];
    const float* cv1_s = (const float*)d_in[2];
    const float* cv1_b = (const float*)d_in[3];
    const float* m1a_w = (const float*)d_in[4];
    const float* m1a_s = (const float*)d_in[5];
    const float* m1a_b = (const float*)d_in[6];
    const float* m1b_w = (const float*)d_in[7];
    const float* m1b_s = (const float*)d_in[8];
    const float* m1b_b = (const float*)d_in[9];
    const float* m2a_w = (const float*)d_in[10];
    const float* m2a_s = (const float*)d_in[11];
    const float* m2a_b = (const float*)d_in[12];
    const float* m2b_w = (const float*)d_in[13];
    const float* m2b_s = (const float*)d_in[14];
    const float* m2b_b = (const float*)d_in[15];
    const float* m3a_w = (const float*)d_in[16];
    const float* m3a_s = (const float*)d_in[17];
    const float* m3a_b = (const float*)d_in[18];
    const float* m3b_w = (const float*)d_in[19];
    const float* m3b_s = (const float*)d_in[20];
    const float* m3b_b = (const float*)d_in[21];
    const float* cvm2_w = (const float*)d_in[22];
    const float* cvm2_s = (const float*)d_in[23];
    const float* cvm2_b = (const float*)d_in[24];
    const float* cvm3_w = (const float*)d_in[25];
    const float* cvm3_s = (const float*)d_in[26];
    const float* cvm3_b = (const float*)d_in[27];
    // d_in[28..31]: u2_down_w/b, u2_enc_w/b — dead (k=1 softmax == 1)
    const float* u3_down_w = (const float*)d_in[32];
    const float* u3_down_b = (const float*)d_in[33];
    const float* u3_enc_w  = (const float*)d_in[34];
    const float* u3_enc_b  = (const float*)d_in[35];
    const float* cv2_w = (const float*)d_in[36];
    const float* cv2_s = (const float*)d_in[37];
    const float* cv2_b = (const float*)d_in[38];

    char* ws = (char*)d_ws;
    u16* A    = (u16*)(ws + 0);          // x_nhwc (67MB); later y2/y3
    u16* t    = (u16*)(ws + 67108864);   // 67MB
    u16* y1   = (u16*)(ws + 134217728);  // 33.5MB
    u16* bt   = (u16*)(ws + 167772160);  // 33.5MB bneck tmp
    u16* te   = (u16*)(ws + 201326592);  // 33.5MB y2b / y3b
    u16* y2a  = (u16*)(ws + 234881024);  // 8.4MB
    u16* y3a  = (u16*)(ws + 243269632);  // 2.1MB
    float* ktA = (float*)(ws + 245366784);  // 1MB fp32
    float* wts = (float*)(ws + 246415360);  // 2MB fp32
    u16* w3t  = (u16*)(ws + 248512512);  // 6 x 147456 bf16
    u16* wu2  = (u16*)(ws + 250281984);  // 65536 bf16
    u16* wu4  = (u16*)(ws + 250413056);  // 262144 bf16
    u16* wc1  = (u16*)(ws + 250937344);  // 65536 bf16
    u16* wc2  = (u16*)(ws + 251068416);  // 163840 bf16
    u16* y2 = A;
    u16* y3 = A + 16777216;

    dim3 B(256);
    // weight conversions / reshuffles
    wtrans3<<<576, B, 0, stream>>>(m1a_w, w3t + 0 * 147456);
    wtrans3<<<576, B, 0, stream>>>(m1b_w, w3t + 1 * 147456);
    wtrans3<<<576, B, 0, stream>>>(m2a_w, w3t + 2 * 147456);
    wtrans3<<<576, B, 0, stream>>>(m2b_w, w3t + 3 * 147456);
    wtrans3<<<576, B, 0, stream>>>(m3a_w, w3t + 4 * 147456);
    wtrans3<<<576, B, 0, stream>>>(m3b_w, w3t + 5 * 147456);
    wtrans_ps<<<256, B, 0, stream>>>(cvm2_w, wu2, 4);
    wtrans_ps<<<1024, B, 0, stream>>>(cvm3_w, wu4, 16);
    cvtw<<<256, B, 0, stream>>>(cv1_w, wc1, 65536);
    cvtw<<<640, B, 0, stream>>>(cv2_w, wc2, 163840);

    // x -> NHWC bf16
    nchw2nhwc<<<dim3(256, 4, 8), B, 0, stream>>>(x, A);

    // cv1 (1x1 256->256) -> t  (y = ch 0..127, y0 = ch 128..255)
    conv_mfma<1, 1, 1, 0, 256><<<dim3(256, 4, 8), B, 0, stream>>>(
        A, 0, 256, wc1, cv1_s, cv1_b, t, 128, 128, 128, 256);

    // bneck1: y0 -> bt -> y1
    conv_mfma<3, 3, 1, 1, 128><<<dim3(256, 2, 8), B, 0, stream>>>(
        t, 128, 256, w3t + 0 * 147456, m1a_s, m1a_b, bt, 128, 128, 128, 128);
    conv_mfma<3, 3, 1, 1, 128><<<dim3(256, 2, 8), B, 0, stream>>>(
        bt, 0, 128, w3t + 1 * 147456, m1b_s, m1b_b, y1, 128, 128, 128, 128);

    // cvm2: pixel_unshuffle(y1,2) + 1x1 == 2x2/stride2 conv -> y2a (64x64)
    conv_mfma<2, 2, 2, 0, 128><<<dim3(64, 2, 8), B, 0, stream>>>(
        y1, 0, 128, wu2, cvm2_s, cvm2_b, y2a, 128, 128, 64, 128);

    // u2 carafe == nearest 2x upsample, + y1 -> te
    k_upadd<<<8192, B, 0, stream>>>(y2a, y1, te);

    // bneck2: te -> bt -> y2
    conv_mfma<3, 3, 1, 1, 128><<<dim3(256, 2, 8), B, 0, stream>>>(
        te, 0, 128, w3t + 2 * 147456, m2a_s, m2a_b, bt, 128, 128, 128, 128);
    conv_mfma<3, 3, 1, 1, 128><<<dim3(256, 2, 8), B, 0, stream>>>(
        bt, 0, 128, w3t + 3 * 147456, m2b_s, m2b_b, y2, 128, 128, 128, 128);

    // cvm3: pixel_unshuffle(y2,4) + 1x1 == 4x4/stride4 conv -> y3a (32x32)
    conv_mfma<4, 4, 4, 0, 128><<<dim3(16, 2, 8), B, 0, stream>>>(
        y2, 0, 128, wu4, cvm3_s, cvm3_b, y3a, 128, 128, 32, 128);

    // u3 carafe (k=2, up=4)
    k_u3down<<<1024, B, 0, stream>>>(y3a, u3_down_w, u3_down_b, ktA);
    k_u3enc<<<512, B, 0, stream>>>(ktA, u3_enc_w, u3_enc_b, wts);
    k_carafe<<<8192, B, 0, stream>>>(y3a, wts, y2, te);

    // bneck3: te -> bt -> y3
    conv_mfma<3, 3, 1, 1, 128><<<dim3(256, 2, 8), B, 0, stream>>>(
        te, 0, 128, w3t + 4 * 147456, m3a_s, m3a_b, bt, 128, 128, 128, 128);
    conv_mfma<3, 3, 1, 1, 128><<<dim3(256, 2, 8), B, 0, stream>>>(
        bt, 0, 128, w3t + 5 * 147456, m3b_s, m3b_b, y3, 128, 128, 128, 128);

    // cv2: 1x1 over concat [t, y1, y2, y3] -> d_out (NCHW fp32)
    conv_cat_mfma<<<dim3(256, 4, 8), B, 0, stream>>>(
        t, y1, y2, y3, wc2, cv2_s, cv2_b, (float*)d_out);
}

// Round 3
// 1400.093 us; speedup vs baseline: 1.7776x; 1.7776x over previous
//
#include <hip/hip_runtime.h>

typedef unsigned short u16;
typedef short v8s __attribute__((ext_vector_type(8)));
typedef u16 v8u __attribute__((ext_vector_type(8)));
typedef float v4f __attribute__((ext_vector_type(4)));
typedef __bf16 v8bf __attribute__((ext_vector_type(8)));

__device__ __forceinline__ float bf2f(u16 u) {
    unsigned x = ((unsigned)u) << 16; float f; __builtin_memcpy(&f, &x, 4); return f;
}
__device__ __forceinline__ u16 f2bf(float f) {
    unsigned x; __builtin_memcpy(&x, &f, 4);
    x = x + 0x7FFFu + ((x >> 16) & 1u);
    return (u16)(x >> 16);
}
__device__ __forceinline__ float silu(float v) { return v / (1.f + __expf(-v)); }

// ---------------------------------------------------------------------------
// Weight conversion / reshuffle kernels (fp32 in -> bf16 out)
// ---------------------------------------------------------------------------
__global__ void cvtw(const float* __restrict__ in, u16* __restrict__ out, int n) {
    int i = blockIdx.x * 256 + threadIdx.x;
    if (i < n) out[i] = f2bf(in[i]);
}
// 3x3: in[co][ci][tap(9)] -> out[tap][co][ci]   (128x128x9)
__global__ void wtrans3(const float* __restrict__ in, u16* __restrict__ out) {
    int i = blockIdx.x * 256 + threadIdx.x;
    if (i >= 147456) return;
    int tap = i % 9; int rem = i / 9; int ci = rem & 127; int co = rem >> 7;
    out[((tap * 128 + co) << 7) + ci] = f2bf(in[i]);
}
// pixel-unshuffle 1x1: in[co][c*R2+tap] -> out[tap][co][c]  (co=128, c=128)
__global__ void wtrans_ps(const float* __restrict__ in, u16* __restrict__ out, int R2) {
    int i = blockIdx.x * 256 + threadIdx.x;
    int tap = i % R2; int rem = i / R2; int c = rem & 127; int co = rem >> 7;
    out[((tap * 128 + co) << 7) + c] = f2bf(in[i]);
}

// ---------------------------------------------------------------------------
// NCHW fp32 -> NHWC bf16 transpose for x (C=256, HW=16384)
// ---------------------------------------------------------------------------
__global__ __launch_bounds__(256) void nchw2nhwc(const float* __restrict__ in, u16* __restrict__ out) {
    __shared__ u16 tile[64][72];
    const int n = blockIdx.z, c0 = blockIdx.y * 64, p0 = blockIdx.x * 64;
#pragma unroll
    for (int rep = 0; rep < 16; ++rep) {
        int idx = rep * 256 + threadIdx.x;
        int c = idx >> 6, p = idx & 63;
        tile[c][p] = f2bf(in[((size_t)(n * 256 + c0 + c)) * 16384 + p0 + p]);
    }
    __syncthreads();
#pragma unroll
    for (int rep = 0; rep < 16; ++rep) {
        int idx = rep * 256 + threadIdx.x;
        int p = idx >> 6, c = idx & 63;
        out[((size_t)n * 16384 + p0 + p) * 256 + c0 + c] = tile[c][p];
    }
}

// ---------------------------------------------------------------------------
// conv3_mfma: 3x3 stride1 pad1, Cin=128 (slice c0 of srcC), Cout=128,
// H=W=128, NHWC bf16. Block = 1 output row (128 px) x 128 co, 4 waves in
// 2x2 (wr=px half, wc=co half), each wave 64x64 via 4x4 MFMA 16x16x32 tiles.
// LDS: 3 rows x 128 px x 32-ci chunk, +16B pad (2-way bank conflicts = free).
// 9 taps x 16 MFMAs = 144 MFMAs per staging barrier.
// ---------------------------------------------------------------------------
__global__ __launch_bounds__(256) void conv3_mfma(
    const u16* __restrict__ src, int c0, int srcC,
    const u16* __restrict__ wt,  // [9][128][128]
    const float* __restrict__ scale, const float* __restrict__ bias,
    u16* __restrict__ out) {
    __shared__ u16 lds[3][128][40];
    const int n = blockIdx.y, h = blockIdx.x;
    const int tid = threadIdx.x;
    const int lane = tid & 63;
    const int wv = tid >> 6;
    const int r = lane & 15, q = lane >> 4;
    const int wr = wv >> 1, wc = wv & 1;

    v4f acc[4][4];
#pragma unroll
    for (int a = 0; a < 4; ++a)
#pragma unroll
        for (int b = 0; b < 4; ++b) acc[a][b] = (v4f){0.f, 0.f, 0.f, 0.f};

    const size_t rowstride = (size_t)128 * srcC;
    const u16* nbase = src + (size_t)n * 128 * rowstride + c0;

    for (int k0 = 0; k0 < 128; k0 += 32) {
        __syncthreads();
#pragma unroll
        for (int kh = 0; kh < 3; ++kh) {
            int hh = h + kh - 1;
            if ((unsigned)hh < 128u) {
                const u16* g = nbase + (size_t)hh * rowstride + k0;
#pragma unroll
                for (int it = 0; it < 2; ++it) {
                    int t = it * 256 + tid;
                    v8s val = *(const v8s*)(g + (size_t)(t >> 2) * srcC + (t & 3) * 8);
                    *(v8s*)&lds[kh][t >> 2][(t & 3) * 8] = val;
                }
            }
        }
        __syncthreads();
#pragma unroll
        for (int kh = 0; kh < 3; ++kh) {
            int hh = h + kh - 1;
            if ((unsigned)hh >= 128u) continue;
#pragma unroll
            for (int kw = 0; kw < 3; ++kw) {
                int tap = kh * 3 + kw;
                const u16* bb = wt + ((size_t)tap * 128 + wc * 64 + r) * 128 + k0 + q * 8;
                v8bf bfr[4];
#pragma unroll
                for (int nt = 0; nt < 4; ++nt)
                    bfr[nt] = __builtin_bit_cast(v8bf, *(const v8s*)(bb + nt * 16 * 128));
                v8bf afr[4];
#pragma unroll
                for (int mt = 0; mt < 4; ++mt) {
                    int p = wr * 64 + mt * 16 + r + kw - 1;
                    bool vp = (unsigned)p < 128u;
                    int pc = vp ? p : 0;
                    v8s av = *(const v8s*)&lds[kh][pc][q * 8];
                    if (!vp) av = (v8s){0, 0, 0, 0, 0, 0, 0, 0};
                    afr[mt] = __builtin_bit_cast(v8bf, av);
                }
#pragma unroll
                for (int mt = 0; mt < 4; ++mt)
#pragma unroll
                    for (int nt = 0; nt < 4; ++nt)
                        acc[mt][nt] = __builtin_amdgcn_mfma_f32_16x16x32_bf16(
                            afr[mt], bfr[nt], acc[mt][nt], 0, 0, 0);
            }
        }
    }

    const size_t obase = ((size_t)n * 128 + h) * 128;
#pragma unroll
    for (int nt = 0; nt < 4; ++nt) {
        int co = wc * 64 + nt * 16 + r;
        float s = scale[co], bi = bias[co];
#pragma unroll
        for (int mt = 0; mt < 4; ++mt) {
            int p = wr * 64 + mt * 16 + q * 4;
#pragma unroll
            for (int i = 0; i < 4; ++i) {
                float v = acc[mt][nt][i] * s + bi;
                out[(obase + p + i) * 128 + co] = f2bf(silu(v));
            }
        }
    }
}

// ---------------------------------------------------------------------------
// conv1_mfma: 1x1 conv, K=srcC, output NHWC bf16 Cout channels.
// Block: 128 px x 128 co tile, LDS-staged A in 32-ci chunks.
// ---------------------------------------------------------------------------
__global__ __launch_bounds__(256) void conv1_mfma(
    const u16* __restrict__ src, int srcC,
    const u16* __restrict__ wt,  // [Cout][srcC]
    const float* __restrict__ scale, const float* __restrict__ bias,
    u16* __restrict__ out, int Cout) {
    __shared__ u16 lds[128][40];
    const int n = blockIdx.z, co0 = blockIdx.y * 128, px0 = blockIdx.x * 128;
    const int tid = threadIdx.x;
    const int lane = tid & 63, wv = tid >> 6;
    const int r = lane & 15, q = lane >> 4;
    const int wr = wv >> 1, wc = wv & 1;

    v4f acc[4][4];
#pragma unroll
    for (int a = 0; a < 4; ++a)
#pragma unroll
        for (int b = 0; b < 4; ++b) acc[a][b] = (v4f){0.f, 0.f, 0.f, 0.f};

    const u16* abase = src + ((size_t)n * 16384 + px0) * srcC;

    for (int k0 = 0; k0 < srcC; k0 += 32) {
        __syncthreads();
#pragma unroll
        for (int it = 0; it < 2; ++it) {
            int t = it * 256 + tid;
            v8s val = *(const v8s*)(abase + (size_t)(t >> 2) * srcC + (t & 3) * 8 + k0);
            *(v8s*)&lds[t >> 2][(t & 3) * 8] = val;
        }
        __syncthreads();
        const u16* bb = wt + (size_t)(co0 + wc * 64 + r) * srcC + k0 + q * 8;
        v8bf bfr[4];
#pragma unroll
        for (int nt = 0; nt < 4; ++nt)
            bfr[nt] = __builtin_bit_cast(v8bf, *(const v8s*)(bb + (size_t)nt * 16 * srcC));
        v8bf afr[4];
#pragma unroll
        for (int mt = 0; mt < 4; ++mt)
            afr[mt] = __builtin_bit_cast(v8bf, *(const v8s*)&lds[wr * 64 + mt * 16 + r][q * 8]);
#pragma unroll
        for (int mt = 0; mt < 4; ++mt)
#pragma unroll
            for (int nt = 0; nt < 4; ++nt)
                acc[mt][nt] = __builtin_amdgcn_mfma_f32_16x16x32_bf16(
                    afr[mt], bfr[nt], acc[mt][nt], 0, 0, 0);
    }

#pragma unroll
    for (int nt = 0; nt < 4; ++nt) {
        int co = co0 + wc * 64 + nt * 16 + r;
        float s = scale[co], bi = bias[co];
#pragma unroll
        for (int mt = 0; mt < 4; ++mt) {
            int p = px0 + wr * 64 + mt * 16 + q * 4;
#pragma unroll
            for (int i = 0; i < 4; ++i) {
                float v = acc[mt][nt][i] * s + bi;
                out[((size_t)n * 16384 + p + i) * Cout + co] = f2bf(silu(v));
            }
        }
    }
}

// ---------------------------------------------------------------------------
// cat_mfma: cv2 = 1x1 conv over implicit concat [t(256), y1, y2, y3] -> 256,
// LDS-staged A per segment, output NCHW fp32 (16B float4 stores).
// ---------------------------------------------------------------------------
__global__ __launch_bounds__(256) void cat_mfma(
    const u16* __restrict__ s0, const u16* __restrict__ s1,
    const u16* __restrict__ s2, const u16* __restrict__ s3,
    const u16* __restrict__ wt,  // [256][640]
    const float* __restrict__ scale, const float* __restrict__ bias,
    float* __restrict__ out) {
    __shared__ u16 lds[128][40];
    const int n = blockIdx.z, co0 = blockIdx.y * 128, px0 = blockIdx.x * 128;
    const int tid = threadIdx.x;
    const int lane = tid & 63, wv = tid >> 6;
    const int r = lane & 15, q = lane >> 4;
    const int wr = wv >> 1, wc = wv & 1;

    v4f acc[4][4];
#pragma unroll
    for (int a = 0; a < 4; ++a)
#pragma unroll
        for (int b = 0; b < 4; ++b) acc[a][b] = (v4f){0.f, 0.f, 0.f, 0.f};

    const u16* srcs[4] = {s0, s1, s2, s3};
    const int sCq[4] = {256, 128, 128, 128};
    const int kbq[4] = {0, 256, 384, 512};

#pragma unroll
    for (int seg = 0; seg < 4; ++seg) {
        const int sc = sCq[seg];
        const u16* ab = srcs[seg] + ((size_t)n * 16384 + px0) * sc;
        for (int k0 = 0; k0 < sc; k0 += 32) {
            __syncthreads();
#pragma unroll
            for (int it = 0; it < 2; ++it) {
                int t = it * 256 + tid;
                v8s val = *(const v8s*)(ab + (size_t)(t >> 2) * sc + (t & 3) * 8 + k0);
                *(v8s*)&lds[t >> 2][(t & 3) * 8] = val;
            }
            __syncthreads();
            const u16* bb = wt + (size_t)(co0 + wc * 64 + r) * 640 + kbq[seg] + k0 + q * 8;
            v8bf bfr[4];
#pragma unroll
            for (int nt = 0; nt < 4; ++nt)
                bfr[nt] = __builtin_bit_cast(v8bf, *(const v8s*)(bb + nt * 16 * 640));
            v8bf afr[4];
#pragma unroll
            for (int mt = 0; mt < 4; ++mt)
                afr[mt] = __builtin_bit_cast(v8bf, *(const v8s*)&lds[wr * 64 + mt * 16 + r][q * 8]);
#pragma unroll
            for (int mt = 0; mt < 4; ++mt)
#pragma unroll
                for (int nt = 0; nt < 4; ++nt)
                    acc[mt][nt] = __builtin_amdgcn_mfma_f32_16x16x32_bf16(
                        afr[mt], bfr[nt], acc[mt][nt], 0, 0, 0);
        }
    }

#pragma unroll
    for (int nt = 0; nt < 4; ++nt) {
        int co = co0 + wc * 64 + nt * 16 + r;
        float s = scale[co], bi = bias[co];
#pragma unroll
        for (int mt = 0; mt < 4; ++mt) {
            int p = px0 + wr * 64 + mt * 16 + q * 4;
            v4f o;
#pragma unroll
            for (int i = 0; i < 4; ++i) o[i] = silu(acc[mt][nt][i] * s + bi);
            *(v4f*)(out + (size_t)(n * 256 + co) * 16384 + p) = o;
        }
    }
}

// ---------------------------------------------------------------------------
// Generic MFMA conv (kept for cvm2/cvm3 strided taps; minor cost)
// ---------------------------------------------------------------------------
template <int KH, int KW, int S, int PAD, int CIN>
__global__ __launch_bounds__(256) void conv_mfma(
    const u16* __restrict__ src, int c0, int srcC,
    const u16* __restrict__ wt,
    const float* __restrict__ scale, const float* __restrict__ bias,
    u16* __restrict__ out, int Hin, int Win, int Wout, int Cout) {
    const int n = blockIdx.z;
    const int co0 = blockIdx.y * 64;
    const int hw0 = blockIdx.x * 64;
    const int tid = threadIdx.x;
    const int lane = tid & 63, wv = tid >> 6;
    const int r = lane & 15, q = lane >> 4;
    const int wr = wv >> 1, wc = wv & 1;

    const int m0 = hw0 + wr * 32 + r;
    const int m1 = m0 + 16;
    const int h0 = m0 / Wout, w0 = m0 - h0 * Wout;
    const int h1 = m1 / Wout, w1 = m1 - h1 * Wout;

    v4f acc00 = {0.f, 0.f, 0.f, 0.f}, acc01 = {0.f, 0.f, 0.f, 0.f};
    v4f acc10 = {0.f, 0.f, 0.f, 0.f}, acc11 = {0.f, 0.f, 0.f, 0.f};

    const u16* b0base = wt + (size_t)(co0 + wc * 32 + r) * CIN + q * 8;
    const size_t wtap = (size_t)Cout * CIN;

    int tap = 0;
#pragma unroll
    for (int kh = 0; kh < KH; ++kh)
#pragma unroll
        for (int kw = 0; kw < KW; ++kw, ++tap) {
            int ih0 = h0 * S + kh - PAD, iw0 = w0 * S + kw - PAD;
            int ih1 = h1 * S + kh - PAD, iw1 = w1 * S + kw - PAD;
            bool v0 = ((unsigned)ih0 < (unsigned)Hin) & ((unsigned)iw0 < (unsigned)Win);
            bool v1 = ((unsigned)ih1 < (unsigned)Hin) & ((unsigned)iw1 < (unsigned)Win);
            int p0i = v0 ? (n * Hin + ih0) * Win + iw0 : 0;
            int p1i = v1 ? (n * Hin + ih1) * Win + iw1 : 0;
            const u16* a0 = src + (size_t)p0i * srcC + c0 + q * 8;
            const u16* a1 = src + (size_t)p1i * srcC + c0 + q * 8;
            const u16* b0 = b0base + (size_t)tap * wtap;
            const u16* b1 = b0 + (size_t)16 * CIN;
#pragma unroll
            for (int k = 0; k < CIN; k += 32) {
                v8s za = {0, 0, 0, 0, 0, 0, 0, 0};
                v8s a0s = za, a1s = za;
                if (v0) a0s = *(const v8s*)(a0 + k);
                if (v1) a1s = *(const v8s*)(a1 + k);
                v8s b0s = *(const v8s*)(b0 + k);
                v8s b1s = *(const v8s*)(b1 + k);
                v8bf af0 = __builtin_bit_cast(v8bf, a0s);
                v8bf af1 = __builtin_bit_cast(v8bf, a1s);
                v8bf bw0 = __builtin_bit_cast(v8bf, b0s);
                v8bf bw1 = __builtin_bit_cast(v8bf, b1s);
                acc00 = __builtin_amdgcn_mfma_f32_16x16x32_bf16(af0, bw0, acc00, 0, 0, 0);
                acc01 = __builtin_amdgcn_mfma_f32_16x16x32_bf16(af0, bw1, acc01, 0, 0, 0);
                acc10 = __builtin_amdgcn_mfma_f32_16x16x32_bf16(af1, bw0, acc10, 0, 0, 0);
                acc11 = __builtin_amdgcn_mfma_f32_16x16x32_bf16(af1, bw1, acc11, 0, 0, 0);
            }
        }

    const int HWo = gridDim.x * 64;
#pragma unroll
    for (int ct = 0; ct < 2; ++ct) {
        v4f av0 = ct ? acc01 : acc00;
        v4f av1 = ct ? acc11 : acc10;
        int co = co0 + wc * 32 + ct * 16 + r;
        float s = scale[co], bb = bias[co];
        int mb = hw0 + wr * 32 + q * 4;
#pragma unroll
        for (int i = 0; i < 4; ++i) {
            float x0 = av0[i] * s + bb;
            float x1 = av1[i] * s + bb;
            out[((size_t)n * HWo + mb + i) * Cout + co] = f2bf(silu(x0));
            out[((size_t)n * HWo + mb + 16 + i) * Cout + co] = f2bf(silu(x1));
        }
    }
}

// ---------------------------------------------------------------------------
// u2 carafe == nearest 2x upsample (+ residual y1). NHWC bf16, C=128.
// ---------------------------------------------------------------------------
__global__ __launch_bounds__(256) void k_upadd(const u16* __restrict__ y2a,
                                               const u16* __restrict__ y1,
                                               u16* __restrict__ out) {
    int t = blockIdx.x * 256 + threadIdx.x;  // 2,097,152
    int cg = t & 15; int pix = t >> 4;
    int n = pix >> 14; int p = pix & 16383; int ho = p >> 7; int wo = p & 127;
    const u16* a = y2a + ((size_t)((n * 64 + (ho >> 1)) * 64 + (wo >> 1))) * 128 + cg * 8;
    const u16* b = y1 + (size_t)pix * 128 + cg * 8;
    v8s av = *(const v8s*)a;
    v8s bv = *(const v8s*)b;
    v8u o;
#pragma unroll
    for (int e = 0; e < 8; ++e) o[e] = f2bf(bf2f((u16)av[e]) + bf2f((u16)bv[e]));
    *(v8u*)(out + (size_t)pix * 128 + cg * 8) = o;
}

// ---------------------------------------------------------------------------
// u3 carafe pieces (small spatial, scalar fp32 math)
// ---------------------------------------------------------------------------
__global__ __launch_bounds__(256) void k_u3down(const u16* __restrict__ y3a,
                                                const float* __restrict__ w,
                                                const float* __restrict__ b,
                                                float* __restrict__ ktA) {
    int t = blockIdx.x * 256 + threadIdx.x;  // 262,144
    int co = t & 31; int pix = t >> 5;
    const u16* xr = y3a + (size_t)pix * 128;
    const float* wr = w + (size_t)co * 128;
    float acc = b[co];
#pragma unroll 16
    for (int k = 0; k < 128; ++k) acc += bf2f(xr[k]) * wr[k];
    ktA[t] = acc;
}

__global__ __launch_bounds__(256) void k_u3enc(const float* __restrict__ ktA,
                                               const float* __restrict__ ew,
                                               const float* __restrict__ eb,
                                               float* __restrict__ wtsm) {
    int t = blockIdx.x * 256 + threadIdx.x;  // 131,072
    int r = t & 15; int pix = t >> 4;
    int n = pix >> 10; int hw = pix & 1023; int h = hw >> 5; int w = hw & 31;
    float v[4];
#pragma unroll
    for (int kk = 0; kk < 4; ++kk) {
        int co = kk * 16 + r;
        float acc = eb[co];
#pragma unroll
        for (int dh = 0; dh < 2; ++dh)
#pragma unroll
            for (int dw = 0; dw < 2; ++dw) {
                int hh = h - 1 + dh, ww = w - 1 + dw;
                if (hh < 0 || ww < 0) continue;
                const float* kp = ktA + ((size_t)((n * 32 + hh) * 32 + ww)) * 32;
                const float* wp = ew + (size_t)co * 128 + dh * 2 + dw;
                for (int ci = 0; ci < 32; ++ci) acc += kp[ci] * wp[ci * 4];
            }
        v[kk] = acc;
    }
    float mx = fmaxf(fmaxf(v[0], v[1]), fmaxf(v[2], v[3]));
    float e0 = __expf(v[0] - mx), e1 = __expf(v[1] - mx), e2 = __expf(v[2] - mx), e3 = __expf(v[3] - mx);
    float inv = 1.f / (e0 + e1 + e2 + e3);
    float* o = wtsm + (size_t)t * 4;
    o[0] = e0 * inv; o[1] = e1 * inv; o[2] = e2 * inv; o[3] = e3 * inv;
}

__global__ __launch_bounds__(256) void k_carafe(const u16* __restrict__ y3a,
                                                const float* __restrict__ wtsm,
                                                const u16* __restrict__ y2,
                                                u16* __restrict__ out) {
    int t = blockIdx.x * 256 + threadIdx.x;  // 2,097,152
    int cg = t & 15; int pix = t >> 4;
    int n = pix >> 14; int p = pix & 16383; int ho = p >> 7; int wo = p & 127;
    int h = ho >> 2, i = ho & 3, w = wo >> 2, j = wo & 3, r = i * 4 + j;
    const float* wv = wtsm + ((size_t)((n * 1024 + h * 32 + w) * 16 + r)) * 4;
    v8s yv = *(const v8s*)(y2 + (size_t)pix * 128 + cg * 8);
    float acc[8];
#pragma unroll
    for (int e = 0; e < 8; ++e) acc[e] = bf2f((u16)yv[e]);
#pragma unroll
    for (int kk = 0; kk < 4; ++kk) {
        int ki = kk >> 1, kj = kk & 1;
        int hh = h + ki - 1, ww = w + kj - 1;
        if (hh < 0 || ww < 0) continue;
        float wk = wv[kk];
        v8s sv = *(const v8s*)(y3a + ((size_t)((n * 32 + hh) * 32 + ww)) * 128 + cg * 8);
#pragma unroll
        for (int e = 0; e < 8; ++e) acc[e] += wk * bf2f((u16)sv[e]);
    }
    v8u o;
#pragma unroll
    for (int e = 0; e < 8; ++e) o[e] = f2bf(acc[e]);
    *(v8u*)(out + (size_t)pix * 128 + cg * 8) = o;
}

// ---------------------------------------------------------------------------
extern "C" void kernel_launch(void* const* d_in, const int* in_sizes, int n_in,
                              void* d_out, int out_size, void* d_ws, size_t ws_size,
                              hipStream_t stream) {
    const float* x     = (const float*)d_in[0];
    const float* cv1_w = (const float*)d_in[1];
    const float* cv1_s = (const float*)d_in[2];
    const float* cv1_b = (const float*)d_in[3];
    const float* m1a_w = (const float*)d_in[4];
    const float* m1a_s = (const float*)d_in[5];
    const float* m1a_b = (const float*)d_in[6];
    const float* m1b_w = (const float*)d_in[7];
    const float* m1b_s = (const float*)d_in[8];
    const float* m1b_b = (const float*)d_in[9];
    const float* m2a_w = (const float*)d_in[10];
    const float* m2a_s = (const float*)d_in[11];
    const float* m2a_b = (const float*)d_in[12];
    const float* m2b_w = (const float*)d_in[13];
    const float* m2b_s = (const float*)d_in[14];
    const float* m2b_b = (const float*)d_in[15];
    const float* m3a_w = (const float*)d_in[16];
    const float* m3a_s = (const float*)d_in[17];
    const float* m3a_b = (const float*)d_in[18];
    const float* m3b_w = (const float*)d_in[19];
    const float* m3b_s = (const float*)d_in[20];
    const float* m3b_b = (const float*)d_in[21];
    const float* cvm2_w = (const float*)d_in[22];
    const float* cvm2_s = (const float*)d_in[23];
    const float* cvm2_b = (const float*)d_in[24];
    const float* cvm3_w = (const float*)d_in[25];
    const float* cvm3_s = (const float*)d_in[26];
    const float* cvm3_b = (const float*)d_in[27];
    // d_in[28..31]: u2_down_w/b, u2_enc_w/b — dead (k=1 softmax == 1)
    const float* u3_down_w = (const float*)d_in[32];
    const float* u3_down_b = (const float*)d_in[33];
    const float* u3_enc_w  = (const float*)d_in[34];
    const float* u3_enc_b  = (const float*)d_in[35];
    const float* cv2_w = (const float*)d_in[36];
    const float* cv2_s = (const float*)d_in[37];
    const float* cv2_b = (const float*)d_in[38];

    char* ws = (char*)d_ws;
    u16* A    = (u16*)(ws + 0);          // x_nhwc (67MB); later y2/y3
    u16* t    = (u16*)(ws + 67108864);   // 67MB
    u16* y1   = (u16*)(ws + 134217728);  // 33.5MB
    u16* bt   = (u16*)(ws + 167772160);  // 33.5MB bneck tmp
    u16* te   = (u16*)(ws + 201326592);  // 33.5MB y2b / y3b
    u16* y2a  = (u16*)(ws + 234881024);  // 8.4MB
    u16* y3a  = (u16*)(ws + 243269632);  // 2.1MB
    float* ktA = (float*)(ws + 245366784);  // 1MB fp32
    float* wts = (float*)(ws + 246415360);  // 2MB fp32
    u16* w3t  = (u16*)(ws + 248512512);  // 6 x 147456 bf16
    u16* wu2  = (u16*)(ws + 250281984);  // 65536 bf16
    u16* wu4  = (u16*)(ws + 250413056);  // 262144 bf16
    u16* wc1  = (u16*)(ws + 250937344);  // 65536 bf16
    u16* wc2  = (u16*)(ws + 251068416);  // 163840 bf16
    u16* y2 = A;
    u16* y3 = A + 16777216;

    dim3 B(256);
    // weight conversions / reshuffles
    wtrans3<<<576, B, 0, stream>>>(m1a_w, w3t + 0 * 147456);
    wtrans3<<<576, B, 0, stream>>>(m1b_w, w3t + 1 * 147456);
    wtrans3<<<576, B, 0, stream>>>(m2a_w, w3t + 2 * 147456);
    wtrans3<<<576, B, 0, stream>>>(m2b_w, w3t + 3 * 147456);
    wtrans3<<<576, B, 0, stream>>>(m3a_w, w3t + 4 * 147456);
    wtrans3<<<576, B, 0, stream>>>(m3b_w, w3t + 5 * 147456);
    wtrans_ps<<<256, B, 0, stream>>>(cvm2_w, wu2, 4);
    wtrans_ps<<<1024, B, 0, stream>>>(cvm3_w, wu4, 16);
    cvtw<<<256, B, 0, stream>>>(cv1_w, wc1, 65536);
    cvtw<<<640, B, 0, stream>>>(cv2_w, wc2, 163840);

    // x -> NHWC bf16
    nchw2nhwc<<<dim3(256, 4, 8), B, 0, stream>>>(x, A);

    // cv1 (1x1 256->256) -> t  (y = ch 0..127, y0 = ch 128..255)
    conv1_mfma<<<dim3(128, 2, 8), B, 0, stream>>>(A, 256, wc1, cv1_s, cv1_b, t, 256);

    // bneck1: y0 -> bt -> y1
    conv3_mfma<<<dim3(128, 8), B, 0, stream>>>(t, 128, 256, w3t + 0 * 147456, m1a_s, m1a_b, bt);
    conv3_mfma<<<dim3(128, 8), B, 0, stream>>>(bt, 0, 128, w3t + 1 * 147456, m1b_s, m1b_b, y1);

    // cvm2: pixel_unshuffle(y1,2) + 1x1 == 2x2/stride2 conv -> y2a (64x64)
    conv_mfma<2, 2, 2, 0, 128><<<dim3(64, 2, 8), B, 0, stream>>>(
        y1, 0, 128, wu2, cvm2_s, cvm2_b, y2a, 128, 128, 64, 128);

    // u2 carafe == nearest 2x upsample, + y1 -> te
    k_upadd<<<8192, B, 0, stream>>>(y2a, y1, te);

    // bneck2: te -> bt -> y2
    conv3_mfma<<<dim3(128, 8), B, 0, stream>>>(te, 0, 128, w3t + 2 * 147456, m2a_s, m2a_b, bt);
    conv3_mfma<<<dim3(128, 8), B, 0, stream>>>(bt, 0, 128, w3t + 3 * 147456, m2b_s, m2b_b, y2);

    // cvm3: pixel_unshuffle(y2,4) + 1x1 == 4x4/stride4 conv -> y3a (32x32)
    conv_mfma<4, 4, 4, 0, 128><<<dim3(16, 2, 8), B, 0, stream>>>(
        y2, 0, 128, wu4, cvm3_s, cvm3_b, y3a, 128, 128, 32, 128);

    // u3 carafe (k=2, up=4)
    k_u3down<<<1024, B, 0, stream>>>(y3a, u3_down_w, u3_down_b, ktA);
    k_u3enc<<<512, B, 0, stream>>>(ktA, u3_enc_w, u3_enc_b, wts);
    k_carafe<<<8192, B, 0, stream>>>(y3a, wts, y2, te);

    // bneck3: te -> bt -> y3
    conv3_mfma<<<dim3(128, 8), B, 0, stream>>>(te, 0, 128, w3t + 4 * 147456, m3a_s, m3a_b, bt);
    conv3_mfma<<<dim3(128, 8), B, 0, stream>>>(bt, 0, 128, w3t + 5 * 147456, m3b_s, m3b_b, y3);

    // cv2: 1x1 over concat [t, y1, y2, y3] -> d_out (NCHW fp32)
    cat_mfma<<<dim3(128, 2, 8), B, 0, stream>>>(t, y1, y2, y3, wc2, cv2_s, cv2_b, (float*)d_out);
}

// Round 4
// 1353.585 us; speedup vs baseline: 1.8387x; 1.0344x over previous
//
#include <hip/hip_runtime.h>

typedef unsigned short u16;
typedef short v8s __attribute__((ext_vector_type(8)));
typedef u16 v8u __attribute__((ext_vector_type(8)));
typedef float v4f __attribute__((ext_vector_type(4)));
typedef __bf16 v8bf __attribute__((ext_vector_type(8)));

__device__ __forceinline__ float bf2f(u16 u) {
    unsigned x = ((unsigned)u) << 16; float f; __builtin_memcpy(&f, &x, 4); return f;
}
__device__ __forceinline__ u16 f2bf(float f) {
    unsigned x; __builtin_memcpy(&x, &f, 4);
    x = x + 0x7FFFu + ((x >> 16) & 1u);
    return (u16)(x >> 16);
}
__device__ __forceinline__ float silu(float v) { return v / (1.f + __expf(-v)); }

// async global->LDS 16B per lane; l must be wave-uniform, data lands at l+lane*16
__device__ __forceinline__ void gld16(const void* g, void* l) {
    __builtin_amdgcn_global_load_lds(
        (const __attribute__((address_space(1))) unsigned int*)(uintptr_t)g,
        (__attribute__((address_space(3))) unsigned int*)(unsigned int)(uintptr_t)l,
        16, 0, 0);
}

// ---------------------------------------------------------------------------
// Weight conversion / reshuffle kernels (fp32 in -> bf16 out)
// ---------------------------------------------------------------------------
__global__ void cvtw(const float* __restrict__ in, u16* __restrict__ out, int n) {
    int i = blockIdx.x * 256 + threadIdx.x;
    if (i < n) out[i] = f2bf(in[i]);
}
// 3x3: in[co][ci][tap(9)] -> out[tap][co][ci]   (128x128x9)
__global__ void wtrans3(const float* __restrict__ in, u16* __restrict__ out) {
    int i = blockIdx.x * 256 + threadIdx.x;
    if (i >= 147456) return;
    int tap = i % 9; int rem = i / 9; int ci = rem & 127; int co = rem >> 7;
    out[((tap * 128 + co) << 7) + ci] = f2bf(in[i]);
}
// pixel-unshuffle 1x1: in[co][c*R2+tap] -> out[tap][co][c]  (co=128, c=128)
__global__ void wtrans_ps(const float* __restrict__ in, u16* __restrict__ out, int R2) {
    int i = blockIdx.x * 256 + threadIdx.x;
    int tap = i % R2; int rem = i / R2; int c = rem & 127; int co = rem >> 7;
    out[((tap * 128 + co) << 7) + c] = f2bf(in[i]);
}

// ---------------------------------------------------------------------------
// NCHW fp32 -> NHWC bf16 transpose for x (C=256, HW=16384)
// ---------------------------------------------------------------------------
__global__ __launch_bounds__(256) void nchw2nhwc(const float* __restrict__ in, u16* __restrict__ out) {
    __shared__ u16 tile[64][72];
    const int n = blockIdx.z, c0 = blockIdx.y * 64, p0 = blockIdx.x * 64;
#pragma unroll
    for (int rep = 0; rep < 16; ++rep) {
        int idx = rep * 256 + threadIdx.x;
        int c = idx >> 6, p = idx & 63;
        tile[c][p] = f2bf(in[((size_t)(n * 256 + c0 + c)) * 16384 + p0 + p]);
    }
    __syncthreads();
#pragma unroll
    for (int rep = 0; rep < 16; ++rep) {
        int idx = rep * 256 + threadIdx.x;
        int p = idx >> 6, c = idx & 63;
        out[((size_t)n * 16384 + p0 + p) * 256 + c0 + c] = tile[c][p];
    }
}

// ---------------------------------------------------------------------------
// conv3_mfma: 3x3 s1 p1, Cin=128 (slice c0 of srcC), Cout=128, H=W=128.
// Block = 1 output row (128 px) x 128 co, 4 waves 2x2, wave = 64px x 64co.
// LDS: [3][128px][32ci] bf16, no pad, filled via global_load_lds (16B/lane).
// Per k0(32): 144 MFMA/wave between barrier pairs.
// ---------------------------------------------------------------------------
__global__ __launch_bounds__(256) void conv3_mfma(
    const u16* __restrict__ src, int c0, int srcC,
    const u16* __restrict__ wt,  // [9][128][128]
    const float* __restrict__ scale, const float* __restrict__ bias,
    u16* __restrict__ out) {
    __shared__ u16 lds[3][128][32];
    const int n = blockIdx.y, h = blockIdx.x;
    const int tid = threadIdx.x;
    const int lane = tid & 63;
    const int wv = tid >> 6;
    const int r = lane & 15, q = lane >> 4;
    const int wr = wv >> 1, wc = wv & 1;

    v4f acc[4][4];
#pragma unroll
    for (int a = 0; a < 4; ++a)
#pragma unroll
        for (int b = 0; b < 4; ++b) acc[a][b] = (v4f){0.f, 0.f, 0.f, 0.f};

    const size_t rowstride = (size_t)128 * srcC;
    const u16* nbase = src + (size_t)n * 128 * rowstride + c0;

    for (int k0 = 0; k0 < 128; k0 += 32) {
        __syncthreads();
        // stage 3 rows x 128px x 32ci (8KB each) via async DMA
#pragma unroll
        for (int kh = 0; kh < 3; ++kh) {
            int hh = h + kh - 1;
            if ((unsigned)hh < 128u) {
                const u16* g = nbase + (size_t)hh * rowstride + k0;
#pragma unroll
                for (int j = 0; j < 2; ++j) {
                    int o = j * 4096 + tid * 16;  // byte offset in 8KB tile
                    int px = o >> 6, cb = o & 63;
                    gld16((const char*)(g + (size_t)px * srcC) + cb,
                          (char*)&lds[kh][0][0] + j * 4096 + wv * 1024);
                }
            }
        }
        __syncthreads();  // barrier drains vmcnt -> LDS valid
#pragma unroll
        for (int kh = 0; kh < 3; ++kh) {
            int hh = h + kh - 1;
            if ((unsigned)hh >= 128u) continue;
#pragma unroll
            for (int kw = 0; kw < 3; ++kw) {
                int tap = kh * 3 + kw;
                const u16* bb = wt + ((size_t)tap * 128 + wc * 64 + r) * 128 + k0 + q * 8;
                v8bf bfr[4];
#pragma unroll
                for (int nt = 0; nt < 4; ++nt)
                    bfr[nt] = __builtin_bit_cast(v8bf, *(const v8s*)(bb + nt * 16 * 128));
                v8bf afr[4];
#pragma unroll
                for (int mt = 0; mt < 4; ++mt) {
                    int p = wr * 64 + mt * 16 + r + kw - 1;
                    bool vp = (unsigned)p < 128u;
                    int pc = vp ? p : 0;
                    v8s av = *(const v8s*)&lds[kh][pc][q * 8];
                    if (!vp) av = (v8s){0, 0, 0, 0, 0, 0, 0, 0};
                    afr[mt] = __builtin_bit_cast(v8bf, av);
                }
#pragma unroll
                for (int mt = 0; mt < 4; ++mt)
#pragma unroll
                    for (int nt = 0; nt < 4; ++nt)
                        acc[mt][nt] = __builtin_amdgcn_mfma_f32_16x16x32_bf16(
                            afr[mt], bfr[nt], acc[mt][nt], 0, 0, 0);
            }
        }
    }

    const size_t obase = ((size_t)n * 128 + h) * 128;
#pragma unroll
    for (int nt = 0; nt < 4; ++nt) {
        int co = wc * 64 + nt * 16 + r;
        float s = scale[co], bi = bias[co];
#pragma unroll
        for (int mt = 0; mt < 4; ++mt) {
            int p = wr * 64 + mt * 16 + q * 4;
#pragma unroll
            for (int i = 0; i < 4; ++i) {
                float v = acc[mt][nt][i] * s + bi;
                out[(obase + p + i) * 128 + co] = f2bf(silu(v));
            }
        }
    }
}

// ---------------------------------------------------------------------------
// conv1_mfma: 1x1 conv, K=srcC, output NHWC bf16. Block 128px x 128co,
// LDS [128px][64ci] (16KB) via global_load_lds, K-chunk 64.
// ---------------------------------------------------------------------------
__global__ __launch_bounds__(256) void conv1_mfma(
    const u16* __restrict__ src, int srcC,
    const u16* __restrict__ wt,  // [Cout][srcC]
    const float* __restrict__ scale, const float* __restrict__ bias,
    u16* __restrict__ out, int Cout) {
    __shared__ u16 lds[128][64];
    const int n = blockIdx.z, co0 = blockIdx.y * 128, px0 = blockIdx.x * 128;
    const int tid = threadIdx.x;
    const int lane = tid & 63, wv = tid >> 6;
    const int r = lane & 15, q = lane >> 4;
    const int wr = wv >> 1, wc = wv & 1;

    v4f acc[4][4];
#pragma unroll
    for (int a = 0; a < 4; ++a)
#pragma unroll
        for (int b = 0; b < 4; ++b) acc[a][b] = (v4f){0.f, 0.f, 0.f, 0.f};

    const u16* abase = src + ((size_t)n * 16384 + px0) * srcC;

    for (int k0 = 0; k0 < srcC; k0 += 64) {
        __syncthreads();
#pragma unroll
        for (int j = 0; j < 4; ++j) {
            int o = j * 4096 + tid * 16;  // byte offset in 16KB tile
            int px = o >> 7, cb = o & 127;
            gld16((const char*)(abase + (size_t)px * srcC + k0) + cb,
                  (char*)&lds[0][0] + j * 4096 + wv * 1024);
        }
        __syncthreads();
#pragma unroll
        for (int s = 0; s < 2; ++s) {
            const u16* bb = wt + (size_t)(co0 + wc * 64 + r) * srcC + k0 + s * 32 + q * 8;
            v8bf bfr[4];
#pragma unroll
            for (int nt = 0; nt < 4; ++nt)
                bfr[nt] = __builtin_bit_cast(v8bf, *(const v8s*)(bb + (size_t)nt * 16 * srcC));
            v8bf afr[4];
#pragma unroll
            for (int mt = 0; mt < 4; ++mt)
                afr[mt] = __builtin_bit_cast(v8bf, *(const v8s*)&lds[wr * 64 + mt * 16 + r][s * 32 + q * 8]);
#pragma unroll
            for (int mt = 0; mt < 4; ++mt)
#pragma unroll
                for (int nt = 0; nt < 4; ++nt)
                    acc[mt][nt] = __builtin_amdgcn_mfma_f32_16x16x32_bf16(
                        afr[mt], bfr[nt], acc[mt][nt], 0, 0, 0);
        }
    }

#pragma unroll
    for (int nt = 0; nt < 4; ++nt) {
        int co = co0 + wc * 64 + nt * 16 + r;
        float s = scale[co], bi = bias[co];
#pragma unroll
        for (int mt = 0; mt < 4; ++mt) {
            int p = px0 + wr * 64 + mt * 16 + q * 4;
#pragma unroll
            for (int i = 0; i < 4; ++i) {
                float v = acc[mt][nt][i] * s + bi;
                out[((size_t)n * 16384 + p + i) * Cout + co] = f2bf(silu(v));
            }
        }
    }
}

// ---------------------------------------------------------------------------
// cat_mfma: cv2 = 1x1 over implicit concat [t(256), y1, y2, y3] -> 256.
// Same structure as conv1 (K-chunk 64); output NCHW fp32 (float4 stores).
// ---------------------------------------------------------------------------
__global__ __launch_bounds__(256) void cat_mfma(
    const u16* __restrict__ s0, const u16* __restrict__ s1,
    const u16* __restrict__ s2, const u16* __restrict__ s3,
    const u16* __restrict__ wt,  // [256][640]
    const float* __restrict__ scale, const float* __restrict__ bias,
    float* __restrict__ out) {
    __shared__ u16 lds[128][64];
    const int n = blockIdx.z, co0 = blockIdx.y * 128, px0 = blockIdx.x * 128;
    const int tid = threadIdx.x;
    const int lane = tid & 63, wv = tid >> 6;
    const int r = lane & 15, q = lane >> 4;
    const int wr = wv >> 1, wc = wv & 1;

    v4f acc[4][4];
#pragma unroll
    for (int a = 0; a < 4; ++a)
#pragma unroll
        for (int b = 0; b < 4; ++b) acc[a][b] = (v4f){0.f, 0.f, 0.f, 0.f};

    const u16* srcs[4] = {s0, s1, s2, s3};
    const int sCq[4] = {256, 128, 128, 128};
    const int kbq[4] = {0, 256, 384, 512};

#pragma unroll
    for (int seg = 0; seg < 4; ++seg) {
        const int sc = sCq[seg];
        const u16* ab = srcs[seg] + ((size_t)n * 16384 + px0) * sc;
        for (int k0 = 0; k0 < sc; k0 += 64) {
            __syncthreads();
#pragma unroll
            for (int j = 0; j < 4; ++j) {
                int o = j * 4096 + tid * 16;
                int px = o >> 7, cb = o & 127;
                gld16((const char*)(ab + (size_t)px * sc + k0) + cb,
                      (char*)&lds[0][0] + j * 4096 + wv * 1024);
            }
            __syncthreads();
#pragma unroll
            for (int s = 0; s < 2; ++s) {
                const u16* bb = wt + (size_t)(co0 + wc * 64 + r) * 640 + kbq[seg] + k0 + s * 32 + q * 8;
                v8bf bfr[4];
#pragma unroll
                for (int nt = 0; nt < 4; ++nt)
                    bfr[nt] = __builtin_bit_cast(v8bf, *(const v8s*)(bb + nt * 16 * 640));
                v8bf afr[4];
#pragma unroll
                for (int mt = 0; mt < 4; ++mt)
                    afr[mt] = __builtin_bit_cast(v8bf, *(const v8s*)&lds[wr * 64 + mt * 16 + r][s * 32 + q * 8]);
#pragma unroll
                for (int mt = 0; mt < 4; ++mt)
#pragma unroll
                    for (int nt = 0; nt < 4; ++nt)
                        acc[mt][nt] = __builtin_amdgcn_mfma_f32_16x16x32_bf16(
                            afr[mt], bfr[nt], acc[mt][nt], 0, 0, 0);
            }
        }
    }

#pragma unroll
    for (int nt = 0; nt < 4; ++nt) {
        int co = co0 + wc * 64 + nt * 16 + r;
        float s = scale[co], bi = bias[co];
#pragma unroll
        for (int mt = 0; mt < 4; ++mt) {
            int p = px0 + wr * 64 + mt * 16 + q * 4;
            v4f o;
#pragma unroll
            for (int i = 0; i < 4; ++i) o[i] = silu(acc[mt][nt][i] * s + bi);
            *(v4f*)(out + (size_t)(n * 256 + co) * 16384 + p) = o;
        }
    }
}

// ---------------------------------------------------------------------------
// Generic MFMA conv (kept for cvm2/cvm3 strided taps; minor cost)
// ---------------------------------------------------------------------------
template <int KH, int KW, int S, int PAD, int CIN>
__global__ __launch_bounds__(256) void conv_mfma(
    const u16* __restrict__ src, int c0, int srcC,
    const u16* __restrict__ wt,
    const float* __restrict__ scale, const float* __restrict__ bias,
    u16* __restrict__ out, int Hin, int Win, int Wout, int Cout) {
    const int n = blockIdx.z;
    const int co0 = blockIdx.y * 64;
    const int hw0 = blockIdx.x * 64;
    const int tid = threadIdx.x;
    const int lane = tid & 63, wv = tid >> 6;
    const int r = lane & 15, q = lane >> 4;
    const int wr = wv >> 1, wc = wv & 1;

    const int m0 = hw0 + wr * 32 + r;
    const int m1 = m0 + 16;
    const int h0 = m0 / Wout, w0 = m0 - h0 * Wout;
    const int h1 = m1 / Wout, w1 = m1 - h1 * Wout;

    v4f acc00 = {0.f, 0.f, 0.f, 0.f}, acc01 = {0.f, 0.f, 0.f, 0.f};
    v4f acc10 = {0.f, 0.f, 0.f, 0.f}, acc11 = {0.f, 0.f, 0.f, 0.f};

    const u16* b0base = wt + (size_t)(co0 + wc * 32 + r) * CIN + q * 8;
    const size_t wtap = (size_t)Cout * CIN;

    int tap = 0;
#pragma unroll
    for (int kh = 0; kh < KH; ++kh)
#pragma unroll
        for (int kw = 0; kw < KW; ++kw, ++tap) {
            int ih0 = h0 * S + kh - PAD, iw0 = w0 * S + kw - PAD;
            int ih1 = h1 * S + kh - PAD, iw1 = w1 * S + kw - PAD;
            bool v0 = ((unsigned)ih0 < (unsigned)Hin) & ((unsigned)iw0 < (unsigned)Win);
            bool v1 = ((unsigned)ih1 < (unsigned)Hin) & ((unsigned)iw1 < (unsigned)Win);
            int p0i = v0 ? (n * Hin + ih0) * Win + iw0 : 0;
            int p1i = v1 ? (n * Hin + ih1) * Win + iw1 : 0;
            const u16* a0 = src + (size_t)p0i * srcC + c0 + q * 8;
            const u16* a1 = src + (size_t)p1i * srcC + c0 + q * 8;
            const u16* b0 = b0base + (size_t)tap * wtap;
            const u16* b1 = b0 + (size_t)16 * CIN;
#pragma unroll
            for (int k = 0; k < CIN; k += 32) {
                v8s za = {0, 0, 0, 0, 0, 0, 0, 0};
                v8s a0s = za, a1s = za;
                if (v0) a0s = *(const v8s*)(a0 + k);
                if (v1) a1s = *(const v8s*)(a1 + k);
                v8s b0s = *(const v8s*)(b0 + k);
                v8s b1s = *(const v8s*)(b1 + k);
                v8bf af0 = __builtin_bit_cast(v8bf, a0s);
                v8bf af1 = __builtin_bit_cast(v8bf, a1s);
                v8bf bw0 = __builtin_bit_cast(v8bf, b0s);
                v8bf bw1 = __builtin_bit_cast(v8bf, b1s);
                acc00 = __builtin_amdgcn_mfma_f32_16x16x32_bf16(af0, bw0, acc00, 0, 0, 0);
                acc01 = __builtin_amdgcn_mfma_f32_16x16x32_bf16(af0, bw1, acc01, 0, 0, 0);
                acc10 = __builtin_amdgcn_mfma_f32_16x16x32_bf16(af1, bw0, acc10, 0, 0, 0);
                acc11 = __builtin_amdgcn_mfma_f32_16x16x32_bf16(af1, bw1, acc11, 0, 0, 0);
            }
        }

    const int HWo = gridDim.x * 64;
#pragma unroll
    for (int ct = 0; ct < 2; ++ct) {
        v4f av0 = ct ? acc01 : acc00;
        v4f av1 = ct ? acc11 : acc10;
        int co = co0 + wc * 32 + ct * 16 + r;
        float s = scale[co], bb = bias[co];
        int mb = hw0 + wr * 32 + q * 4;
#pragma unroll
        for (int i = 0; i < 4; ++i) {
            float x0 = av0[i] * s + bb;
            float x1 = av1[i] * s + bb;
            out[((size_t)n * HWo + mb + i) * Cout + co] = f2bf(silu(x0));
            out[((size_t)n * HWo + mb + 16 + i) * Cout + co] = f2bf(silu(x1));
        }
    }
}

// ---------------------------------------------------------------------------
// u2 carafe == nearest 2x upsample (+ residual y1). NHWC bf16, C=128.
// ---------------------------------------------------------------------------
__global__ __launch_bounds__(256) void k_upadd(const u16* __restrict__ y2a,
                                               const u16* __restrict__ y1,
                                               u16* __restrict__ out) {
    int t = blockIdx.x * 256 + threadIdx.x;  // 2,097,152
    int cg = t & 15; int pix = t >> 4;
    int n = pix >> 14; int p = pix & 16383; int ho = p >> 7; int wo = p & 127;
    const u16* a = y2a + ((size_t)((n * 64 + (ho >> 1)) * 64 + (wo >> 1))) * 128 + cg * 8;
    const u16* b = y1 + (size_t)pix * 128 + cg * 8;
    v8s av = *(const v8s*)a;
    v8s bv = *(const v8s*)b;
    v8u o;
#pragma unroll
    for (int e = 0; e < 8; ++e) o[e] = f2bf(bf2f((u16)av[e]) + bf2f((u16)bv[e]));
    *(v8u*)(out + (size_t)pix * 128 + cg * 8) = o;
}

// ---------------------------------------------------------------------------
// u3 carafe pieces (small spatial, scalar fp32 math)
// ---------------------------------------------------------------------------
__global__ __launch_bounds__(256) void k_u3down(const u16* __restrict__ y3a,
                                                const float* __restrict__ w,
                                                const float* __restrict__ b,
                                                float* __restrict__ ktA) {
    int t = blockIdx.x * 256 + threadIdx.x;  // 262,144
    int co = t & 31; int pix = t >> 5;
    const u16* xr = y3a + (size_t)pix * 128;
    const float* wr = w + (size_t)co * 128;
    float acc = b[co];
#pragma unroll 16
    for (int k = 0; k < 128; ++k) acc += bf2f(xr[k]) * wr[k];
    ktA[t] = acc;
}

__global__ __launch_bounds__(256) void k_u3enc(const float* __restrict__ ktA,
                                               const float* __restrict__ ew,
                                               const float* __restrict__ eb,
                                               float* __restrict__ wtsm) {
    int t = blockIdx.x * 256 + threadIdx.x;  // 131,072
    int r = t & 15; int pix = t >> 4;
    int n = pix >> 10; int hw = pix & 1023; int h = hw >> 5; int w = hw & 31;
    float v[4];
#pragma unroll
    for (int kk = 0; kk < 4; ++kk) {
        int co = kk * 16 + r;
        float acc = eb[co];
#pragma unroll
        for (int dh = 0; dh < 2; ++dh)
#pragma unroll
            for (int dw = 0; dw < 2; ++dw) {
                int hh = h - 1 + dh, ww = w - 1 + dw;
                if (hh < 0 || ww < 0) continue;
                const float* kp = ktA + ((size_t)((n * 32 + hh) * 32 + ww)) * 32;
                const float* wp = ew + (size_t)co * 128 + dh * 2 + dw;
                for (int ci = 0; ci < 32; ++ci) acc += kp[ci] * wp[ci * 4];
            }
        v[kk] = acc;
    }
    float mx = fmaxf(fmaxf(v[0], v[1]), fmaxf(v[2], v[3]));
    float e0 = __expf(v[0] - mx), e1 = __expf(v[1] - mx), e2 = __expf(v[2] - mx), e3 = __expf(v[3] - mx);
    float inv = 1.f / (e0 + e1 + e2 + e3);
    float* o = wtsm + (size_t)t * 4;
    o[0] = e0 * inv; o[1] = e1 * inv; o[2] = e2 * inv; o[3] = e3 * inv;
}

__global__ __launch_bounds__(256) void k_carafe(const u16* __restrict__ y3a,
                                                const float* __restrict__ wtsm,
                                                const u16* __restrict__ y2,
                                                u16* __restrict__ out) {
    int t = blockIdx.x * 256 + threadIdx.x;  // 2,097,152
    int cg = t & 15; int pix = t >> 4;
    int n = pix >> 14; int p = pix & 16383; int ho = p >> 7; int wo = p & 127;
    int h = ho >> 2, i = ho & 3, w = wo >> 2, j = wo & 3, r = i * 4 + j;
    const float* wv = wtsm + ((size_t)((n * 1024 + h * 32 + w) * 16 + r)) * 4;
    v8s yv = *(const v8s*)(y2 + (size_t)pix * 128 + cg * 8);
    float acc[8];
#pragma unroll
    for (int e = 0; e < 8; ++e) acc[e] = bf2f((u16)yv[e]);
#pragma unroll
    for (int kk = 0; kk < 4; ++kk) {
        int ki = kk >> 1, kj = kk & 1;
        int hh = h + ki - 1, ww = w + kj - 1;
        if (hh < 0 || ww < 0) continue;
        float wk = wv[kk];
        v8s sv = *(const v8s*)(y3a + ((size_t)((n * 32 + hh) * 32 + ww)) * 128 + cg * 8);
#pragma unroll
        for (int e = 0; e < 8; ++e) acc[e] += wk * bf2f((u16)sv[e]);
    }
    v8u o;
#pragma unroll
    for (int e = 0; e < 8; ++e) o[e] = f2bf(acc[e]);
    *(v8u*)(out + (size_t)pix * 128 + cg * 8) = o;
}

// ---------------------------------------------------------------------------
extern "C" void kernel_launch(void* const* d_in, const int* in_sizes, int n_in,
                              void* d_out, int out_size, void* d_ws, size_t ws_size,
                              hipStream_t stream) {
    const float* x     = (const float*)d_in[0];
    const float* cv1_w = (const float*)d_in[1];
    const float* cv1_s = (const float*)d_in[2];
    const float* cv1_b = (const float*)d_in[3];
    const float* m1a_w = (const float*)d_in[4];
    const float* m1a_s = (const float*)d_in[5];
    const float* m1a_b = (const float*)d_in[6];
    const float* m1b_w = (const float*)d_in[7];
    const float* m1b_s = (const float*)d_in[8];
    const float* m1b_b = (const float*)d_in[9];
    const float* m2a_w = (const float*)d_in[10];
    const float* m2a_s = (const float*)d_in[11];
    const float* m2a_b = (const float*)d_in[12];
    const float* m2b_w = (const float*)d_in[13];
    const float* m2b_s = (const float*)d_in[14];
    const float* m2b_b = (const float*)d_in[15];
    const float* m3a_w = (const float*)d_in[16];
    const float* m3a_s = (const float*)d_in[17];
    const float* m3a_b = (const float*)d_in[18];
    const float* m3b_w = (const float*)d_in[19];
    const float* m3b_s = (const float*)d_in[20];
    const float* m3b_b = (const float*)d_in[21];
    const float* cvm2_w = (const float*)d_in[22];
    const float* cvm2_s = (const float*)d_in[23];
    const float* cvm2_b = (const float*)d_in[24];
    const float* cvm3_w = (const float*)d_in[25];
    const float* cvm3_s = (const float*)d_in[26];
    const float* cvm3_b = (const float*)d_in[27];
    // d_in[28..31]: u2_down_w/b, u2_enc_w/b — dead (k=1 softmax == 1)
    const float* u3_down_w = (const float*)d_in[32];
    const float* u3_down_b = (const float*)d_in[33];
    const float* u3_enc_w  = (const float*)d_in[34];
    const float* u3_enc_b  = (const float*)d_in[35];
    const float* cv2_w = (const float*)d_in[36];
    const float* cv2_s = (const float*)d_in[37];
    const float* cv2_b = (const float*)d_in[38];

    char* ws = (char*)d_ws;
    u16* A    = (u16*)(ws + 0);          // x_nhwc (67MB); later y2/y3
    u16* t    = (u16*)(ws + 67108864);   // 67MB
    u16* y1   = (u16*)(ws + 134217728);  // 33.5MB
    u16* bt   = (u16*)(ws + 167772160);  // 33.5MB bneck tmp
    u16* te   = (u16*)(ws + 201326592);  // 33.5MB y2b / y3b
    u16* y2a  = (u16*)(ws + 234881024);  // 8.4MB
    u16* y3a  = (u16*)(ws + 243269632);  // 2.1MB
    float* ktA = (float*)(ws + 245366784);  // 1MB fp32
    float* wts = (float*)(ws + 246415360);  // 2MB fp32
    u16* w3t  = (u16*)(ws + 248512512);  // 6 x 147456 bf16
    u16* wu2  = (u16*)(ws + 250281984);  // 65536 bf16
    u16* wu4  = (u16*)(ws + 250413056);  // 262144 bf16
    u16* wc1  = (u16*)(ws + 250937344);  // 65536 bf16
    u16* wc2  = (u16*)(ws + 251068416);  // 163840 bf16
    u16* y2 = A;
    u16* y3 = A + 16777216;

    dim3 B(256);
    // weight conversions / reshuffles
    wtrans3<<<576, B, 0, stream>>>(m1a_w, w3t + 0 * 147456);
    wtrans3<<<576, B, 0, stream>>>(m1b_w, w3t + 1 * 147456);
    wtrans3<<<576, B, 0, stream>>>(m2a_w, w3t + 2 * 147456);
    wtrans3<<<576, B, 0, stream>>>(m2b_w, w3t + 3 * 147456);
    wtrans3<<<576, B, 0, stream>>>(m3a_w, w3t + 4 * 147456);
    wtrans3<<<576, B, 0, stream>>>(m3b_w, w3t + 5 * 147456);
    wtrans_ps<<<256, B, 0, stream>>>(cvm2_w, wu2, 4);
    wtrans_ps<<<1024, B, 0, stream>>>(cvm3_w, wu4, 16);
    cvtw<<<256, B, 0, stream>>>(cv1_w, wc1, 65536);
    cvtw<<<640, B, 0, stream>>>(cv2_w, wc2, 163840);

    // x -> NHWC bf16
    nchw2nhwc<<<dim3(256, 4, 8), B, 0, stream>>>(x, A);

    // cv1 (1x1 256->256) -> t  (y = ch 0..127, y0 = ch 128..255)
    conv1_mfma<<<dim3(128, 2, 8), B, 0, stream>>>(A, 256, wc1, cv1_s, cv1_b, t, 256);

    // bneck1: y0 -> bt -> y1
    conv3_mfma<<<dim3(128, 8), B, 0, stream>>>(t, 128, 256, w3t + 0 * 147456, m1a_s, m1a_b, bt);
    conv3_mfma<<<dim3(128, 8), B, 0, stream>>>(bt, 0, 128, w3t + 1 * 147456, m1b_s, m1b_b, y1);

    // cvm2: pixel_unshuffle(y1,2) + 1x1 == 2x2/stride2 conv -> y2a (64x64)
    conv_mfma<2, 2, 2, 0, 128><<<dim3(64, 2, 8), B, 0, stream>>>(
        y1, 0, 128, wu2, cvm2_s, cvm2_b, y2a, 128, 128, 64, 128);

    // u2 carafe == nearest 2x upsample, + y1 -> te
    k_upadd<<<8192, B, 0, stream>>>(y2a, y1, te);

    // bneck2: te -> bt -> y2
    conv3_mfma<<<dim3(128, 8), B, 0, stream>>>(te, 0, 128, w3t + 2 * 147456, m2a_s, m2a_b, bt);
    conv3_mfma<<<dim3(128, 8), B, 0, stream>>>(bt, 0, 128, w3t + 3 * 147456, m2b_s, m2b_b, y2);

    // cvm3: pixel_unshuffle(y2,4) + 1x1 == 4x4/stride4 conv -> y3a (32x32)
    conv_mfma<4, 4, 4, 0, 128><<<dim3(16, 2, 8), B, 0, stream>>>(
        y2, 0, 128, wu4, cvm3_s, cvm3_b, y3a, 128, 128, 32, 128);

    // u3 carafe (k=2, up=4)
    k_u3down<<<1024, B, 0, stream>>>(y3a, u3_down_w, u3_down_b, ktA);
    k_u3enc<<<512, B, 0, stream>>>(ktA, u3_enc_w, u3_enc_b, wts);
    k_carafe<<<8192, B, 0, stream>>>(y3a, wts, y2, te);

    // bneck3: te -> bt -> y3
    conv3_mfma<<<dim3(128, 8), B, 0, stream>>>(te, 0, 128, w3t + 4 * 147456, m3a_s, m3a_b, bt);
    conv3_mfma<<<dim3(128, 8), B, 0, stream>>>(bt, 0, 128, w3t + 5 * 147456, m3b_s, m3b_b, y3);

    // cv2: 1x1 over concat [t, y1, y2, y3] -> d_out (NCHW fp32)
    cat_mfma<<<dim3(128, 2, 8), B, 0, stream>>>(t, y1, y2, y3, wc2, cv2_s, cv2_b, (float*)d_out);
}